// Round 15
// baseline (545.205 us; speedup 1.0000x reference)
//
#include <hip/hip_runtime.h>
#include <hip/hip_bf16.h>
#include <math.h>

#define BB 4
#define TT 2048
#define DD 256
#define FF 1024
#define NL 4

typedef __bf16 bf16x8 __attribute__((ext_vector_type(8)));
typedef float f32x4 __attribute__((ext_vector_type(4)));
typedef __hip_bfloat16 bf16;

// fast exact-GELU: 0.5x(1+erf(x/sqrt2)), erf via A&S 7.1.26 (|err|<1.5e-7)
__device__ __forceinline__ float gelu_f(float v) {
  float x = fabsf(v) * 0.70710678118654752f;
  float t = 1.0f / fmaf(0.3275911f, x, 1.0f);
  float p = t * fmaf(t, fmaf(t, fmaf(t, fmaf(t, 1.061405429f, -1.453152027f),
                                     1.421413741f), -0.284496736f), 0.254829592f);
  float erfv = copysignf(1.0f - p * __expf(-x * x), v);
  return 0.5f * v * (1.0f + erfv);
}

// ---------------- prologue: weight f32->bf16 (blocks 0..3071) + PE+LN0 (rest) ----
__global__ __launch_bounds__(256) void prologue_kernel(
    const float4* __restrict__ wq, const float4* __restrict__ wo,
    const float4* __restrict__ w1, const float4* __restrict__ w2,
    ushort4* __restrict__ dst,
    const float* __restrict__ tokens, const float* __restrict__ g,
    const float* __restrict__ b, float* __restrict__ x,
    bf16* __restrict__ sb) {
  if (blockIdx.x < 3072) {
    int gi = blockIdx.x * 256 + threadIdx.x;
    const float4* src;
    int off;
    if (gi < 196608)      { src = wq; off = gi; }
    else if (gi < 262144) { src = wo; off = gi - 196608; }
    else if (gi < 524288) { src = w1; off = gi - 262144; }
    else                  { src = w2; off = gi - 524288; }
    float4 v = src[off];
    ushort4 o;
    o.x = __hip_bfloat16_raw(__float2bfloat16(v.x)).x;
    o.y = __hip_bfloat16_raw(__float2bfloat16(v.y)).x;
    o.z = __hip_bfloat16_raw(__float2bfloat16(v.z)).x;
    o.w = __hip_bfloat16_raw(__float2bfloat16(v.w)).x;
    dst[gi] = o;
    return;
  }
  int row = (blockIdx.x - 3072) * 4 + (threadIdx.x >> 6);
  int lane = threadIdx.x & 63;
  int t = row & (TT - 1);
  const float* xr = tokens + (size_t)row * DD;
  float v[4];
  float s = 0.f;
#pragma unroll
  for (int i = 0; i < 4; ++i) {
    int d = lane + 64 * i;
    float freq = expf((float)(d & ~1) * -(9.210340371976184f / 256.f));
    float ang = (float)t * freq;
    float pe = (d & 1) ? cosf(ang) : sinf(ang);
    v[i] = xr[d] + pe;
    s += v[i];
  }
#pragma unroll
  for (int off = 32; off; off >>= 1) s += __shfl_xor(s, off, 64);
  float mu = s * (1.f / DD);
  float vs = 0.f;
#pragma unroll
  for (int i = 0; i < 4; ++i) { float dd = v[i] - mu; vs = fmaf(dd, dd, vs); }
#pragma unroll
  for (int off = 32; off; off >>= 1) vs += __shfl_xor(vs, off, 64);
  float rr = rsqrtf(vs * (1.f / DD) + 1e-5f);
#pragma unroll
  for (int i = 0; i < 4; ++i) {
    int d = lane + 64 * i;
    x[(size_t)row * DD + d] = v[i];
    sb[(size_t)row * DD + d] = __float2bfloat16((v[i] - mu) * rr * g[d] + b[d]);
  }
}

// ---------------- register-direct bf16 MFMA GEMM: NO LDS, NO barriers ----------
// Block = 4 waves in 2x2; block tile (32MW)x(32NW); wave tile (16MW)x(16NW).
// MFMA fragments loaded straight from global (16 B/lane dwordx4); the compiler
// pipelines the loads across unrolled K-iterations with fine-grained vmcnt.
// XCD swizzle: xcd=bid&7 owns m-band. OUTF: 0=bf16 out, 1=fp32 out.
template <int MW, int NW, int KTOT, int ACT, int OUTF>
__global__ __launch_bounds__(256) void rgemm_kernel(
    const bf16* __restrict__ A, const bf16* __restrict__ B,
    const float* __restrict__ bias, void* __restrict__ Cout,
    int N, int nN, int nM) {
  const int tid = threadIdx.x;
  const int wave = tid >> 6, lane = tid & 63;
  const int bid = blockIdx.x;
  const int xcd = bid & 7, kk = bid >> 3;
  const int mt = xcd * (nM >> 3) + kk / nN;
  const int nt = kk - (kk / nN) * nN;
  const int quad = lane >> 4, lr = lane & 15;
  const int m0 = mt * (32 * MW) + (wave >> 1) * (16 * MW);
  const int n0 = nt * (32 * NW) + (wave & 1) * (16 * NW);

  const bf16* arow = A + (size_t)(m0 + lr) * KTOT + quad * 8;
  const bf16* brow = B + (size_t)(n0 + lr) * KTOT + quad * 8;

  f32x4 acc[MW][NW] = {};

#pragma unroll 4
  for (int kt = 0; kt < KTOT; kt += 32) {
    bf16x8 af[MW], bfr[NW];
#pragma unroll
    for (int mi = 0; mi < MW; ++mi)
      af[mi] = *(const bf16x8*)(arow + (size_t)mi * 16 * KTOT + kt);
#pragma unroll
    for (int ni = 0; ni < NW; ++ni)
      bfr[ni] = *(const bf16x8*)(brow + (size_t)ni * 16 * KTOT + kt);
#pragma unroll
    for (int mi = 0; mi < MW; ++mi)
#pragma unroll
      for (int ni = 0; ni < NW; ++ni)
        acc[mi][ni] = __builtin_amdgcn_mfma_f32_16x16x32_bf16(
            af[mi], bfr[ni], acc[mi][ni], 0, 0, 0);
  }

#pragma unroll
  for (int mi = 0; mi < MW; ++mi)
#pragma unroll
    for (int ni = 0; ni < NW; ++ni) {
      int col = n0 + ni * 16 + lr;
      float bv = bias[col];
#pragma unroll
      for (int r = 0; r < 4; ++r) {
        int row = m0 + mi * 16 + quad * 4 + r;
        float v = acc[mi][ni][r] + bv;
        if (ACT == 1) v = gelu_f(v);
        if (OUTF) ((float*)Cout)[(size_t)row * N + col] = v;
        else ((bf16*)Cout)[(size_t)row * N + col] = __float2bfloat16(v);
      }
    }
}

// ---------------- register-direct Wo GEMM + residual + LN (BM=16, grid 512) ----
// GEMM part barrier-free; single barrier for the cross-wave LN reduction.
__global__ __launch_bounds__(256) void rgemm_ln_kernel(
    const bf16* __restrict__ A, const bf16* __restrict__ B,
    const float* __restrict__ bias, const float* __restrict__ res,
    const float* __restrict__ g, const float* __restrict__ bb,
    float* __restrict__ xout, bf16* __restrict__ yout) {
  constexpr int KTOT = 256;
  __shared__ float red1[4][16], red2[4][16];
  const int tid = threadIdx.x;
  const int wave = tid >> 6, lane = tid & 63;
  const int quad = lane >> 4, lr = lane & 15;
  const int m0 = blockIdx.x * 16;

  const bf16* arow = A + (size_t)(m0 + lr) * KTOT + quad * 8;
  const bf16* brow = B + (size_t)(wave * 64 + lr) * KTOT + quad * 8;

  f32x4 acc[4] = {};
#pragma unroll 4
  for (int kt = 0; kt < KTOT; kt += 32) {
    bf16x8 af = *(const bf16x8*)(arow + kt);
    bf16x8 bfr[4];
#pragma unroll
    for (int ni = 0; ni < 4; ++ni)
      bfr[ni] = *(const bf16x8*)(brow + (size_t)ni * 16 * KTOT + kt);
#pragma unroll
    for (int ni = 0; ni < 4; ++ni)
      acc[ni] = __builtin_amdgcn_mfma_f32_16x16x32_bf16(af, bfr[ni], acc[ni], 0, 0, 0);
  }

  // epilogue: v = acc + bias + res; LN over the 16 rows (full 256 cols)
  float v[4][4];
  float s1[4] = {}, s2[4] = {};
#pragma unroll
  for (int ni = 0; ni < 4; ++ni) {
    int col = wave * 64 + ni * 16 + lr;
    float bv = bias[col];
#pragma unroll
    for (int r = 0; r < 4; ++r) {
      int row = m0 + quad * 4 + r;
      float val = acc[ni][r] + bv + res[(size_t)row * DD + col];
      v[ni][r] = val;
      s1[r] += val;
      s2[r] = fmaf(val, val, s2[r]);
    }
  }
#pragma unroll
  for (int r = 0; r < 4; ++r) {
#pragma unroll
    for (int off = 8; off; off >>= 1) {
      s1[r] += __shfl_xor(s1[r], off, 64);
      s2[r] += __shfl_xor(s2[r], off, 64);
    }
  }
  if (lr == 0) {
#pragma unroll
    for (int r = 0; r < 4; ++r) {
      red1[wave][quad * 4 + r] = s1[r];
      red2[wave][quad * 4 + r] = s2[r];
    }
  }
  __syncthreads();
#pragma unroll
  for (int r = 0; r < 4; ++r) {
    int rl = quad * 4 + r;
    float ssum = red1[0][rl] + red1[1][rl] + red1[2][rl] + red1[3][rl];
    float qsum = red2[0][rl] + red2[1][rl] + red2[2][rl] + red2[3][rl];
    float mu = ssum * (1.f / DD);
    float var = qsum * (1.f / DD) - mu * mu;
    float rr = rsqrtf(var + 1e-5f);
    int row = m0 + rl;
#pragma unroll
    for (int ni = 0; ni < 4; ++ni) {
      int col = wave * 64 + ni * 16 + lr;
      float y = (v[ni][r] - mu) * rr * g[col] + bb[col];
      yout[(size_t)row * DD + col] = __float2bfloat16(y);
      xout[(size_t)row * DD + col] = v[ni][r];
    }
  }
}

// ---------------- residual + LayerNorm (elementwise, 1 wave/row, bf16 gout) ----
template <int FIN>
__global__ __launch_bounds__(256) void rln_kernel(
    const bf16* __restrict__ go, const float* __restrict__ xin,
    const float* __restrict__ g, const float* __restrict__ b,
    float* __restrict__ xout, bf16* __restrict__ sbout,
    float* __restrict__ out) {
  int row = blockIdx.x * 4 + (threadIdx.x >> 6);
  int lane = threadIdx.x & 63;
  const bf16* gr = go + (size_t)row * DD;
  const float* xr = xin + (size_t)row * DD;
  float v[4];
  float s = 0.f;
#pragma unroll
  for (int i = 0; i < 4; ++i) {
    int d = lane + 64 * i;
    v[i] = __bfloat162float(gr[d]) + xr[d];
    s += v[i];
  }
#pragma unroll
  for (int off = 32; off; off >>= 1) s += __shfl_xor(s, off, 64);
  float mu = s * (1.f / DD);
  float vs = 0.f;
#pragma unroll
  for (int i = 0; i < 4; ++i) { float dd = v[i] - mu; vs = fmaf(dd, dd, vs); }
#pragma unroll
  for (int off = 32; off; off >>= 1) vs += __shfl_xor(vs, off, 64);
  float rr = rsqrtf(vs * (1.f / DD) + 1e-5f);
#pragma unroll
  for (int i = 0; i < 4; ++i) {
    int d = lane + 64 * i;
    float y = (v[i] - mu) * rr * g[d] + b[d];
    if (FIN) {
      out[(size_t)row * DD + d] = y;
    } else {
      xout[(size_t)row * DD + d] = v[i];
      sbout[(size_t)row * DD + d] = __float2bfloat16(y);
    }
  }
}

// ---------------- sliding-window attention, MFMA (R9/R12, unchanged) ----------------
__global__ __launch_bounds__(256) void attn_kernel(const bf16* __restrict__ qkv,
                                                   bf16* __restrict__ o) {
  __shared__ __align__(16) bf16 KsPs[128 * 72];
  __shared__ __align__(16) bf16 Vt[64 * 136];
  const int bh = blockIdx.y;
  const int b = bh >> 2, h = bh & 3;
  const int t0 = blockIdx.x * 64;
  const int sbase = t0 - 63;
  const int tid = threadIdx.x;

  const bf16* kb = qkv + (size_t)(b * TT) * 768 + 256 + h * 64;
  const bf16* vb = kb + 256;
  union U8 { uint4 u; bf16 hx[8]; };
#pragma unroll
  for (int it = 0; it < 4; ++it) {
    int f = tid + it * 256;
    int si = f >> 3;
    int c8 = f & 7;
    int s = sbase + si;
    U8 kr, vr;
    kr.u = make_uint4(0, 0, 0, 0); vr.u = make_uint4(0, 0, 0, 0);
    if (s >= 0 && s < TT) {
      kr.u = *(const uint4*)&kb[(size_t)s * 768 + 8 * c8];
      vr.u = *(const uint4*)&vb[(size_t)s * 768 + 8 * c8];
    }
    *(uint4*)&KsPs[si * 72 + c8 * 8] = kr.u;
    int pc = (si >> 3) ^ c8;
#pragma unroll
    for (int j = 0; j < 8; ++j) Vt[(c8 * 8 + j) * 136 + pc * 8 + (si & 7)] = vr.hx[j];
  }
  __syncthreads();

  const int wave = tid >> 6, lane = tid & 63;
  const int quad = lane >> 4, lr = lane & 15;

  const bf16* qrow = qkv + (size_t)(b * TT + t0 + wave * 16 + lr) * 768 + h * 64;
  bf16x8 qa0 = *(const bf16x8*)(qrow + quad * 8);
  bf16x8 qa1 = *(const bf16x8*)(qrow + 32 + quad * 8);
  f32x4 sc[8];
#pragma unroll
  for (int c = 0; c < 8; ++c) {
    f32x4 a = {};
    bf16x8 kf0 = *(const bf16x8*)&KsPs[(c * 16 + lr) * 72 + quad * 8];
    a = __builtin_amdgcn_mfma_f32_16x16x32_bf16(qa0, kf0, a, 0, 0, 0);
    bf16x8 kf1 = *(const bf16x8*)&KsPs[(c * 16 + lr) * 72 + 32 + quad * 8];
    a = __builtin_amdgcn_mfma_f32_16x16x32_bf16(qa1, kf1, a, 0, 0, 0);
    sc[c] = a;
  }
  __syncthreads();

#pragma unroll
  for (int reg = 0; reg < 4; ++reg) {
    int dt = wave * 16 + quad * 4 + reg;
    float pv[8];
    float mx = -1e30f;
#pragma unroll
    for (int c = 0; c < 8; ++c) {
      int si = c * 16 + lr;
      float v = sc[c][reg] * 0.125f;
      bool ok = (si >= dt) && (si <= dt + 63) && (sbase + si >= 0);
      v = ok ? v : -1e30f;
      pv[c] = v;
      mx = fmaxf(mx, v);
    }
#pragma unroll
    for (int off = 8; off; off >>= 1) mx = fmaxf(mx, __shfl_xor(mx, off, 64));
    float l = 0.f;
#pragma unroll
    for (int c = 0; c < 8; ++c) { float e = __expf(pv[c] - mx); pv[c] = e; l += e; }
#pragma unroll
    for (int off = 8; off; off >>= 1) l += __shfl_xor(l, off, 64);
    float rinv = 1.f / l;
#pragma unroll
    for (int c = 0; c < 8; ++c)
      KsPs[(wave * 16 + quad * 4 + reg) * 136 + c * 16 + lr] = __float2bfloat16(pv[c] * rinv);
  }

  bf16* obase = o + (size_t)(b * TT) * DD + h * 64;
#pragma unroll
  for (int ct = 0; ct < 4; ++ct) {
    f32x4 acc = {};
#pragma unroll
    for (int kk = 0; kk < 4; ++kk) {
      bf16x8 pa = *(const bf16x8*)&KsPs[(wave * 16 + lr) * 136 + kk * 32 + quad * 8];
      int dd = ct * 16 + lr;
      bf16x8 vf = *(const bf16x8*)&Vt[dd * 136 + (((kk * 4 + quad) ^ (dd >> 3)) * 8)];
      acc = __builtin_amdgcn_mfma_f32_16x16x32_bf16(pa, vf, acc, 0, 0, 0);
    }
#pragma unroll
    for (int reg = 0; reg < 4; ++reg) {
      int t = t0 + wave * 16 + quad * 4 + reg;
      obase[(size_t)t * DD + ct * 16 + lr] = __float2bfloat16(acc[reg]);
    }
  }
}

extern "C" void kernel_launch(void* const* d_in, const int* in_sizes, int n_in,
                              void* d_out, int out_size, void* d_ws, size_t ws_size,
                              hipStream_t stream) {
  const float* tokens = (const float*)d_in[0];
  const float* Wqkv = (const float*)d_in[1];
  const float* bqkv = (const float*)d_in[2];
  const float* Wo   = (const float*)d_in[3];
  const float* bo   = (const float*)d_in[4];
  const float* W1   = (const float*)d_in[5];
  const float* b1   = (const float*)d_in[6];
  const float* W2   = (const float*)d_in[7];
  const float* b2   = (const float*)d_in[8];
  const float* ln1g = (const float*)d_in[9];
  const float* ln1b = (const float*)d_in[10];
  const float* ln2g = (const float*)d_in[11];
  const float* ln2b = (const float*)d_in[12];
  const float* lnfg = (const float*)d_in[13];
  const float* lnfb = (const float*)d_in[14];
  float* out = (float*)d_out;

  const int M = BB * TT;                 // 8192
  const int ND = M * DD;

  float* x = (float*)d_ws;
  bf16* sb  = (bf16*)(x + ND);
  bf16* big = sb + (size_t)M * DD;
  bf16* wqb = big + (size_t)M * FF;
  bf16* wob = wqb + (size_t)NL * 3 * DD * DD;
  bf16* w1b = wob + (size_t)NL * DD * DD;
  bf16* w2b = w1b + (size_t)NL * FF * DD;
  bf16* gbuf = w2b + (size_t)NL * DD * FF;    // W2 raw out, M*256 bf16

  prologue_kernel<<<3072 + M / 4, 256, 0, stream>>>(
      (const float4*)Wqkv, (const float4*)Wo, (const float4*)W1,
      (const float4*)W2, (ushort4*)wqb, tokens, ln1g, ln1b, x, sb);

  // layer-0 qkv: register-direct, 64x128 tiles, 768 blocks
  rgemm_kernel<2, 4, 256, 0, 0><<<768, 256, 0, stream>>>(
      sb, wqb, bqkv, big, 768, 6, 128);

  for (int l = 0; l < NL; ++l) {
    attn_kernel<<<dim3(TT / 64, BB * 4), 256, 0, stream>>>(big, sb);
    // Wo + residual + ln2: register-direct GEMM, BM=16, grid 512
    rgemm_ln_kernel<<<M / 16, 256, 0, stream>>>(
        sb, wob + (size_t)l * DD * DD, bo + l * DD, x,
        ln2g + l * DD, ln2b + l * DD, x, sb);
    // W1 + GELU: register-direct, 64x128 tiles, 1024 blocks
    rgemm_kernel<2, 4, 256, 1, 0><<<1024, 256, 0, stream>>>(
        sb, w1b + (size_t)l * FF * DD, b1 + l * FF, big, FF, 8, 128);
    // W2: register-direct, 64x64 tiles, K=1024, 512 blocks, bf16 out
    rgemm_kernel<2, 2, 1024, 0, 0><<<512, 256, 0, stream>>>(
        big, w2b + (size_t)l * DD * FF, b2 + l * DD, gbuf, DD, 4, 128);
    if (l < NL - 1) {
      rln_kernel<0><<<M / 4, 256, 0, stream>>>(
          gbuf, x, ln1g + (l + 1) * DD, ln1b + (l + 1) * DD, x, sb, nullptr);
      rgemm_kernel<2, 4, 256, 0, 0><<<768, 256, 0, stream>>>(
          sb, wqb + (size_t)(l + 1) * 768 * DD, bqkv + (l + 1) * 768, big, 768, 6, 128);
    } else {
      rln_kernel<1><<<M / 4, 256, 0, stream>>>(
          gbuf, x, lnfg, lnfb, nullptr, nullptr, out);
    }
  }
}